// Round 1
// baseline (711.337 us; speedup 1.0000x reference)
//
#include <hip/hip_runtime.h>
#include <cfloat>

#define LAT_ROWS 32768
#define DIM 512
#define KCODES 1024

constexpr int BM = 64;                 // rows per block
constexpr int BN = 128;                // codes per code-tile
constexpr int BD = 32;                 // d-chunk (floats)
constexpr int NTHREADS = 256;
constexpr int CTILES = KCODES / BN;    // 8
constexpr int DTILES = DIM / BD;       // 16
constexpr int TTOT = CTILES * DTILES;  // 128

// ---------------- codebook norms: one wave per code ----------------
__global__ void vq_norms_kernel(const float* __restrict__ cb,
                                float* __restrict__ norms) {
  const int gw = (int)((blockIdx.x * blockDim.x + threadIdx.x) >> 6);
  const int l = threadIdx.x & 63;
  const float4 a = *(const float4*)&cb[(size_t)gw * DIM + l * 8];
  const float4 b = *(const float4*)&cb[(size_t)gw * DIM + l * 8 + 4];
  float s = a.x * a.x + a.y * a.y + a.z * a.z + a.w * a.w +
            b.x * b.x + b.y * b.y + b.z * b.z + b.w * b.w;
#pragma unroll
  for (int m = 1; m < 64; m <<= 1) s += __shfl_xor(s, m, 64);
  if (l == 0) norms[gw] = s;
}

// ---------------- main: GEMM + argmin + gather + loss ----------------
__global__ void __launch_bounds__(NTHREADS, 2)
vq_main_kernel(const float* __restrict__ X, const float* __restrict__ CB,
               const float* __restrict__ norms, float* __restrict__ outq,
               double* __restrict__ lsum) {
  __shared__ float Xs[2][BM * BD];   // 8 KB x2
  __shared__ float Cs[2][BN * BD];   // 16 KB x2
  __shared__ int idxs[BM];
  __shared__ float wpart[4];

  const int tid = threadIdx.x;
  const int ty = tid >> 4;   // rows ty*4 .. +4
  const int tx = tid & 15;   // codes tx*8 .. +8
  const int row0 = blockIdx.x * BM;

  // Staging descriptors. LDS physical slot (row, qphys) holds global quad
  // qlog = qphys ^ ((row>>3)&7)  (XOR swizzle, involution).
  const float* xsrc[2];
  int xo[2];
#pragma unroll
  for (int k = 0; k < 2; ++k) {
    const int o = (k * NTHREADS + tid) * 4;   // dword offset in 2048-dword tile
    const int row = o >> 5;
    const int q = (o >> 2) & 7;
    const int gq = q ^ ((row >> 3) & 7);
    xo[k] = o;
    xsrc[k] = X + (size_t)(row0 + row) * DIM + gq * 4;
  }
  const float* csrc[4];
  int co[4];
#pragma unroll
  for (int k = 0; k < 4; ++k) {
    const int o = (k * NTHREADS + tid) * 4;   // dword offset in 4096-dword tile
    const int code = o >> 5;
    const int q = (o >> 2) & 7;
    const int gq = q ^ ((code >> 3) & 7);
    co[k] = o;
    csrc[k] = CB + (size_t)code * DIM + gq * 4;
  }

  float acc[4][8];
  float rmin[4];
  int ridx[4];
#pragma unroll
  for (int i = 0; i < 4; ++i) { rmin[i] = FLT_MAX; ridx[i] = 0; }

  // prologue: stage tile 0 into buf 0
  {
#pragma unroll
    for (int k = 0; k < 2; ++k) *(float4*)&Xs[0][xo[k]] = *(const float4*)(xsrc[k]);
#pragma unroll
    for (int k = 0; k < 4; ++k) *(float4*)&Cs[0][co[k]] = *(const float4*)(csrc[k]);
  }
  __syncthreads();

  int buf = 0;
  for (int t = 0; t < TTOT; ++t) {
    const int ct = t >> 4;
    const int dt = t & 15;
    const bool havenext = (t + 1 < TTOT);
    float4 stx[2], stc[4];
    if (havenext) {  // issue next-tile global loads early (hide under MACs)
      const int nt_ = t + 1;
      const int ndt = nt_ & 15;
      const int nct = nt_ >> 4;
      const int xoff = ndt * BD;
      const size_t coff = (size_t)nct * BN * DIM + ndt * BD;
#pragma unroll
      for (int k = 0; k < 2; ++k) stx[k] = *(const float4*)(xsrc[k] + xoff);
#pragma unroll
      for (int k = 0; k < 4; ++k) stc[k] = *(const float4*)(csrc[k] + coff);
    }
    if (dt == 0) {
#pragma unroll
      for (int i = 0; i < 4; ++i)
#pragma unroll
        for (int j = 0; j < 8; ++j) acc[i][j] = 0.f;
    }
    const float* xb = Xs[buf];
    const float* cbt = Cs[buf];
#pragma unroll
    for (int q = 0; q < 8; ++q) {
      float4 xf[4], cf[8];
#pragma unroll
      for (int i = 0; i < 4; ++i) {
        const int row = ty * 4 + i;
        const int pq = q ^ ((row >> 3) & 7);
        xf[i] = *(const float4*)&xb[row * BD + pq * 4];
      }
#pragma unroll
      for (int j = 0; j < 8; ++j) {
        const int code = tx * 8 + j;
        const int pq = q ^ ((code >> 3) & 7);
        cf[j] = *(const float4*)&cbt[code * BD + pq * 4];
      }
#pragma unroll
      for (int i = 0; i < 4; ++i)
#pragma unroll
        for (int j = 0; j < 8; ++j) {
          acc[i][j] = fmaf(xf[i].x, cf[j].x, acc[i][j]);
          acc[i][j] = fmaf(xf[i].y, cf[j].y, acc[i][j]);
          acc[i][j] = fmaf(xf[i].z, cf[j].z, acc[i][j]);
          acc[i][j] = fmaf(xf[i].w, cf[j].w, acc[i][j]);
        }
    }
    if (dt == DTILES - 1) {  // fold this code-tile into running argmin
#pragma unroll
      for (int j = 0; j < 8; ++j) {
        const int code = ct * BN + tx * 8 + j;
        const float cn = norms[code];
#pragma unroll
        for (int i = 0; i < 4; ++i) {
          const float s = fmaf(-2.f, acc[i][j], cn);
          if (s < rmin[i]) { rmin[i] = s; ridx[i] = code; }
        }
      }
    }
    if (havenext) {  // LDS writes after compute (vmcnt hidden under MACs)
      const int nb = buf ^ 1;
#pragma unroll
      for (int k = 0; k < 2; ++k) *(float4*)&Xs[nb][xo[k]] = stx[k];
#pragma unroll
      for (int k = 0; k < 4; ++k) *(float4*)&Cs[nb][co[k]] = stc[k];
    }
    __syncthreads();
    buf ^= 1;
  }

  // cross-tx argmin reduce (16 lanes share each row group; tie -> lowest idx)
#pragma unroll
  for (int m = 1; m < 16; m <<= 1) {
#pragma unroll
    for (int i = 0; i < 4; ++i) {
      const float om = __shfl_xor(rmin[i], m, 64);
      const int oi = __shfl_xor(ridx[i], m, 64);
      if (om < rmin[i] || (om == rmin[i] && oi < ridx[i])) {
        rmin[i] = om;
        ridx[i] = oi;
      }
    }
  }
  if (tx == 0) {
#pragma unroll
    for (int i = 0; i < 4; ++i) idxs[ty * 4 + i] = ridx[i];
  }
  __syncthreads();

  // gather + write quantized + loss partial
  float part = 0.f;
  for (int g = tid; g < BM * (DIM / 4); g += NTHREADS) {
    const int row = g >> 7;
    const int d4 = (g & 127) * 4;
    const int idx = idxs[row];
    const float4 c4 = *(const float4*)&CB[(size_t)idx * DIM + d4];
    const float4 x4 = *(const float4*)&X[(size_t)(row0 + row) * DIM + d4];
    *(float4*)&outq[(size_t)(row0 + row) * DIM + d4] = c4;
    float d_;
    d_ = x4.x - c4.x; part = fmaf(d_, d_, part);
    d_ = x4.y - c4.y; part = fmaf(d_, d_, part);
    d_ = x4.z - c4.z; part = fmaf(d_, d_, part);
    d_ = x4.w - c4.w; part = fmaf(d_, d_, part);
  }
#pragma unroll
  for (int m = 1; m < 64; m <<= 1) part += __shfl_xor(part, m, 64);
  const int lane = tid & 63;
  const int w = tid >> 6;
  if (lane == 0) wpart[w] = part;
  __syncthreads();
  if (tid == 0) {
    const double tot = (double)wpart[0] + (double)wpart[1] +
                       (double)wpart[2] + (double)wpart[3];
    atomicAdd(lsum, tot);
  }
}

__global__ void vq_finalize_kernel(const double* __restrict__ lsum,
                                   float* __restrict__ out) {
  out[0] = (float)(1.25 * lsum[0] / (double)((size_t)LAT_ROWS * DIM));
}

extern "C" void kernel_launch(void* const* d_in, const int* in_sizes, int n_in,
                              void* d_out, int out_size, void* d_ws, size_t ws_size,
                              hipStream_t stream) {
  const float* X = (const float*)d_in[0];     // [32768, 512] f32 (flattened latents)
  const float* CB = (const float*)d_in[1];    // [1024, 512] f32
  float* out = (float*)d_out;                 // [16777216] quantized + [1] loss
  double* lsum = (double*)d_ws;               // 8B accumulator
  float* norms = (float*)((char*)d_ws + 64);  // 1024 f32

  hipMemsetAsync(d_ws, 0, 8, stream);
  vq_norms_kernel<<<KCODES / 4, 256, 0, stream>>>(CB, norms);
  vq_main_kernel<<<LAT_ROWS / BM, NTHREADS, 0, stream>>>(X, CB, norms, out, lsum);
  vq_finalize_kernel<<<1, 1, 0, stream>>>(lsum, out + (size_t)LAT_ROWS * DIM);
}

// Round 2
// 91.551 us; speedup vs baseline: 7.7698x; 7.7698x over previous
//
#include <hip/hip_runtime.h>
#include <cfloat>

#define LAT_ROWS 32768
#define DIM 512
#define KCODES 1024

constexpr int BM = 128;            // latent rows per block
constexpr int BN = 256;            // codes per code-tile
constexpr int BK = 64;             // d-chunk
constexpr int NT = 512;            // threads (8 waves: 4 code-groups x 2 row-groups)
constexpr int NCT = KCODES / BN;   // 4
constexpr int NDK = DIM / BK;      // 8
constexpr int TT = NCT * NDK;      // 32

typedef short bf16x8 __attribute__((ext_vector_type(8)));
typedef float f32x4 __attribute__((ext_vector_type(4)));
typedef unsigned short u16;
typedef u16 u16x8 __attribute__((ext_vector_type(8)));

__device__ __forceinline__ u16 f2bf(float f) {  // round-to-nearest-even
  unsigned u = __float_as_uint(f);
  u += 0x7FFF + ((u >> 16) & 1);
  return (u16)(u >> 16);
}

// ---------------- codebook norms (f32 exact): one wave per code ----------------
__global__ void vq_norms_kernel(const float* __restrict__ cb,
                                float* __restrict__ norms) {
  const int gw = (int)((blockIdx.x * blockDim.x + threadIdx.x) >> 6);
  const int l = threadIdx.x & 63;
  const float4 a = *(const float4*)&cb[(size_t)gw * DIM + l * 8];
  const float4 b = *(const float4*)&cb[(size_t)gw * DIM + l * 8 + 4];
  float s = a.x * a.x + a.y * a.y + a.z * a.z + a.w * a.w +
            b.x * b.x + b.y * b.y + b.z * b.z + b.w * b.w;
#pragma unroll
  for (int m = 1; m < 64; m <<= 1) s += __shfl_xor(s, m, 64);
  if (l == 0) norms[gw] = s;
}

// ---------------- main: bf16 MFMA distance GEMM + argmin + gather + loss ----------------
__global__ void __launch_bounds__(NT, 2)
vq_main(const float* __restrict__ X, const float* __restrict__ CB,
        const float* __restrict__ norms, float* __restrict__ outq,
        double* __restrict__ lsum) {
  __shared__ u16 Xs[2][BM * BK];    // 16 KB x2
  __shared__ u16 Cs[2][BN * BK];    // 32 KB x2
  __shared__ float snorm[KCODES];   // 4 KB
  __shared__ float redm[BM][4];
  __shared__ int redi[BM][4];
  __shared__ int idxs[BM];
  __shared__ float wpart[8];

  const int tid = threadIdx.x;
  const int lane = tid & 63;
  const int l15 = lane & 15;
  const int l4 = lane >> 4;
  const int wid = tid >> 6;
  const int wm = wid & 3;        // code group (64 codes)
  const int wn = wid >> 2;       // row group (64 rows)
  const int row0 = blockIdx.x * BM;

  for (int i = tid; i < KCODES; i += NT) snorm[i] = norms[i];

  // staging geometry: unit = (row, 8-float quad); LDS phys quad = q ^ (row&7)
  int xlds[2]; const float* xbase[2];
#pragma unroll
  for (int k = 0; k < 2; ++k) {
    const int u = tid + k * NT;            // 1024 X units
    const int r = u >> 3, q = u & 7, ph = q ^ (r & 7);
    xlds[k] = r * BK + ph * 8;
    xbase[k] = X + (size_t)(row0 + r) * DIM + q * 8;
  }
  int clds[4]; const float* cbase[4];
#pragma unroll
  for (int k = 0; k < 4; ++k) {
    const int u = tid + k * NT;            // 2048 CB units
    const int r = u >> 3, q = u & 7, ph = q ^ (r & 7);
    clds[k] = r * BK + ph * 8;
    cbase[k] = CB + (size_t)r * DIM + q * 8;
  }

  f32x4 acc[4][4];                 // [mf codes][nf rows]
  float rmin[4]; int ridx[4];
#pragma unroll
  for (int i = 0; i < 4; ++i) { rmin[i] = FLT_MAX; ridx[i] = 0; }
  float sq = 0.f;

  float4 lx[2][2], lc[4][2];
  auto load_tile = [&](int tn) {
    const int ct = tn >> 3, dk = tn & 7;
    const int xo = dk * BK;
    const size_t co = (size_t)ct * BN * DIM + dk * BK;
#pragma unroll
    for (int k = 0; k < 2; ++k) {
      lx[k][0] = *(const float4*)(xbase[k] + xo);
      lx[k][1] = *(const float4*)(xbase[k] + xo + 4);
    }
#pragma unroll
    for (int k = 0; k < 4; ++k) {
      lc[k][0] = *(const float4*)(cbase[k] + co);
      lc[k][1] = *(const float4*)(cbase[k] + co + 4);
    }
  };
  auto write_tile = [&](int b, bool acc_sq) {
#pragma unroll
    for (int k = 0; k < 2; ++k) {
      u16x8 v;
      const float* f = (const float*)&lx[k][0];
#pragma unroll
      for (int j = 0; j < 8; ++j) {
        const float x = f[j];
        if (acc_sq) sq = fmaf(x, x, sq);   // global sum(x^2) for the loss
        v[j] = f2bf(x);
      }
      *(u16x8*)&Xs[b][xlds[k]] = v;
    }
#pragma unroll
    for (int k = 0; k < 4; ++k) {
      u16x8 v;
      const float* f = (const float*)&lc[k][0];
#pragma unroll
      for (int j = 0; j < 8; ++j) v[j] = f2bf(f[j]);
      *(u16x8*)&Cs[b][clds[k]] = v;
    }
  };

  load_tile(0);
  write_tile(0, true);
  __syncthreads();

  int cur = 0;
  for (int t = 0; t < TT; ++t) {
    const int dk = t & 7;
    const bool pre = (t + 1 < TT);
    if (pre) load_tile(t + 1);          // issue next-tile global loads early
    if (dk == 0) {
      const f32x4 z = {0.f, 0.f, 0.f, 0.f};
#pragma unroll
      for (int mf = 0; mf < 4; ++mf)
#pragma unroll
        for (int nf = 0; nf < 4; ++nf) acc[mf][nf] = z;
    }
    const u16* xb = Xs[cur];
    const u16* cb = Cs[cur];
#pragma unroll
    for (int ks = 0; ks < 2; ++ks) {
      bf16x8 af[4], bfr[4];
#pragma unroll
      for (int mf = 0; mf < 4; ++mf) {
        const int r = wm * 64 + mf * 16 + l15;
        const int ph = (ks * 4 + l4) ^ (r & 7);
        af[mf] = *(const bf16x8*)&cb[r * BK + ph * 8];
      }
#pragma unroll
      for (int nf = 0; nf < 4; ++nf) {
        const int r = wn * 64 + nf * 16 + l15;
        const int ph = (ks * 4 + l4) ^ (r & 7);
        bfr[nf] = *(const bf16x8*)&xb[r * BK + ph * 8];
      }
#pragma unroll
      for (int mf = 0; mf < 4; ++mf)
#pragma unroll
        for (int nf = 0; nf < 4; ++nf)
          acc[mf][nf] = __builtin_amdgcn_mfma_f32_16x16x32_bf16(
              af[mf], bfr[nf], acc[mf][nf], 0, 0, 0);
    }
    if (dk == NDK - 1) {  // fold finished code-tile into running argmin
      const int ct = t >> 3;
#pragma unroll
      for (int mf = 0; mf < 4; ++mf) {
#pragma unroll
        for (int r = 0; r < 4; ++r) {
          const int code = ct * BN + wm * 64 + mf * 16 + l4 * 4 + r;
          const float cn = snorm[code];
#pragma unroll
          for (int nf = 0; nf < 4; ++nf) {
            const float s = fmaf(-2.f, acc[mf][nf][r], cn);
            if (s < rmin[nf]) { rmin[nf] = s; ridx[nf] = code; }
          }
        }
      }
    }
    if (pre) write_tile(cur ^ 1, (t + 1) < NDK);  // LDS writes after compute
    __syncthreads();
    cur ^= 1;
  }

  // cross-lane argmin (lanes l, l+16, l+32, l+48 share a row; tie -> lowest idx)
#pragma unroll
  for (int m = 16; m <= 32; m <<= 1) {
#pragma unroll
    for (int nf = 0; nf < 4; ++nf) {
      const float om = __shfl_xor(rmin[nf], m, 64);
      const int oi = __shfl_xor(ridx[nf], m, 64);
      if (om < rmin[nf] || (om == rmin[nf] && oi < ridx[nf])) {
        rmin[nf] = om; ridx[nf] = oi;
      }
    }
  }
  if (l4 == 0) {
#pragma unroll
    for (int nf = 0; nf < 4; ++nf) {
      const int row = wn * 64 + nf * 16 + l15;
      redm[row][wm] = rmin[nf];
      redi[row][wm] = ridx[nf];
    }
  }
  __syncthreads();

  float tot = sq;
  if (tid < BM) {   // cross-wave reduce (4 code-group waves per row)
    float bm = redm[tid][0]; int bi = redi[tid][0];
#pragma unroll
    for (int c = 1; c < 4; ++c) {
      const float m_ = redm[tid][c]; const int i_ = redi[tid][c];
      if (m_ < bm || (m_ == bm && i_ < bi)) { bm = m_; bi = i_; }
    }
    idxs[tid] = bi;
    tot += bm;      // s_min = ||c||^2 - 2 x.c  ->  ||x-q||^2 = x^2-part + s_min
  }
#pragma unroll
  for (int m = 1; m < 64; m <<= 1) tot += __shfl_xor(tot, m, 64);
  if (lane == 0) wpart[wid] = tot;
  __syncthreads();
  if (tid == 0) {
    double s = 0.0;
    for (int i = 0; i < 8; ++i) s += (double)wpart[i];
    atomicAdd(lsum, s);
  }

  // gather + write quantized (exact f32 codebook rows, CB is L2-hot)
  for (int g = tid; g < BM * (DIM / 4); g += NT) {
    const int row = g >> 7;
    const int d4 = (g & 127) * 4;
    const int idx = idxs[row];
    *(float4*)&outq[(size_t)(row0 + row) * DIM + d4] =
        *(const float4*)&CB[(size_t)idx * DIM + d4];
  }
}

__global__ void vq_finalize_kernel(const double* __restrict__ lsum,
                                   float* __restrict__ out) {
  out[0] = (float)(1.25 * lsum[0] / (double)((size_t)LAT_ROWS * DIM));
}

extern "C" void kernel_launch(void* const* d_in, const int* in_sizes, int n_in,
                              void* d_out, int out_size, void* d_ws, size_t ws_size,
                              hipStream_t stream) {
  const float* X = (const float*)d_in[0];     // [32768, 512] f32
  const float* CB = (const float*)d_in[1];    // [1024, 512] f32
  float* out = (float*)d_out;                 // quantized [16777216] + loss [1]
  double* lsum = (double*)d_ws;               // 8B accumulator
  float* norms = (float*)((char*)d_ws + 64);  // 1024 f32

  hipMemsetAsync(d_ws, 0, 8, stream);
  vq_norms_kernel<<<KCODES / 4, 256, 0, stream>>>(CB, norms);
  vq_main<<<LAT_ROWS / BM, NT, 0, stream>>>(X, CB, norms, out, lsum);
  vq_finalize_kernel<<<1, 1, 0, stream>>>(lsum, out + (size_t)LAT_ROWS * DIM);
}